// Round 2
// baseline (2292.794 us; speedup 1.0000x reference)
//
#include <hip/hip_runtime.h>

#define Bsz   1024
#define Tlen  512
#define VOC   8
#define EDIM  32
#define HDIM  64
#define G4    256   // 4*H gate rows
#define NT    512   // threads per block: 2 half-row threads per gate row

// broadcast lane j (wave-uniform index) of a VGPR to all lanes via SGPR
__device__ __forceinline__ float rl(float v, int lane) {
    return __uint_as_float(__builtin_amdgcn_readlane(__float_as_uint(v), lane));
}

__device__ __forceinline__ float sigm(float x) {
    return 1.0f / (1.0f + __expf(-x));
}
__device__ __forceinline__ float tanh_(float x) {
    float e2 = __expf(-2.0f * fabsf(x));          // in (0,1]
    float t  = (1.0f - e2) / (1.0f + e2);
    return copysignf(t, x);
}

// ws layout: [0 .. 8*256) = G0 table (layer0 gates from embedding, incl. both biases)
//            [8*256 .. 8*256+256) = bih1+bhh1
__global__ void precompute_kernel(const float* __restrict__ emb,
                                  const float* __restrict__ Wih0,
                                  const float* __restrict__ bih0,
                                  const float* __restrict__ bhh0,
                                  const float* __restrict__ bih1,
                                  const float* __restrict__ bhh1,
                                  float* __restrict__ ws) {
    int g = threadIdx.x;
    int v = blockIdx.x;
    if (v < VOC) {
        float acc = bih0[g] + bhh0[g];
        #pragma unroll
        for (int e = 0; e < EDIM; ++e)
            acc += Wih0[g * EDIM + e] * emb[v * EDIM + e];
        ws[v * G4 + g] = acc;
    } else {
        ws[VOC * G4 + g] = bih1[g] + bhh1[g];
    }
}

__global__ __launch_bounds__(NT, 4)
void lstm_kernel(const int*   __restrict__ x,
                 const float* __restrict__ Whh0,
                 const float* __restrict__ Wih1,
                 const float* __restrict__ Whh1,
                 const float* __restrict__ Wfc,
                 const float* __restrict__ bfc,
                 const float* __restrict__ ws,
                 float* __restrict__ out) {
    __shared__ float sG0[VOC * G4];   // 8 KB gate table
    __shared__ int   sx[Tlen];        // 2 KB token stream
    __shared__ float sh0[HDIM], sh1[HDIM];
    __shared__ float sact0[G4], sact1[G4];
    __shared__ float sp0[NT], sp1[NT];  // half-row partial sums

    const int tid  = threadIdx.x;
    const int b    = blockIdx.x;
    const int lane = tid & 63;
    const int g    = tid & 255;       // gate row
    const int p    = tid >> 8;        // half: j in [32p, 32p+32)  (wave-uniform)
    const int jb   = p * 32;

    // stage gate table + tokens
    #pragma unroll
    for (int i = 0; i < (VOC * G4) / NT; ++i)
        sG0[i * NT + tid] = ws[i * NT + tid];
    sx[tid] = x[b * Tlen + tid];
    if (tid < HDIM) { sh0[tid] = 0.0f; sh1[tid] = 0.0f; }
    const float b1 = ws[VOC * G4 + g]; // only used by tid<256 combine threads

    // thread (g,p) owns the p-th half of gate-row g of all three matrices: 96 floats
    float w0[32], wi1[32], wh1[32];
    {
        const float4* p0 = (const float4*)(Whh0 + g * HDIM + jb);
        const float4* p1 = (const float4*)(Wih1 + g * HDIM + jb);
        const float4* p2 = (const float4*)(Whh1 + g * HDIM + jb);
        #pragma unroll
        for (int i = 0; i < 8; ++i) {
            float4 a = p0[i];
            w0[4*i+0]=a.x; w0[4*i+1]=a.y; w0[4*i+2]=a.z; w0[4*i+3]=a.w;
            float4 bq = p1[i];
            wi1[4*i+0]=bq.x; wi1[4*i+1]=bq.y; wi1[4*i+2]=bq.z; wi1[4*i+3]=bq.w;
            float4 c = p2[i];
            wh1[4*i+0]=c.x; wh1[4*i+1]=c.y; wh1[4*i+2]=c.z; wh1[4*i+3]=c.w;
        }
    }

    float c0 = 0.0f, c1 = 0.0f;     // lane j of wave0 holds c0[j]; wave1 holds c1[j]
    float vh0 = 0.0f, vh1 = 0.0f;   // lane l holds h0[l], h1[l] (readlane broadcast source)
    __syncthreads();

    // layer1 pipelined one step behind layer0: iter k does layer0@t=k and layer1@t=k-1
    #pragma unroll 1
    for (int k = 0; k <= Tlen; ++k) {
        // phase 1: all 512 threads compute half-row dot products
        float a0 = 0.0f, aw = 0.0f, ah = 0.0f;
        #pragma unroll
        for (int jj = 0; jj < 32; ++jj) {
            const int j = jb + jj;           // wave-uniform lane index
            float h0j = rl(vh0, j);
            float h1j = rl(vh1, j);
            a0 += w0[jj]  * h0j;
            aw += wi1[jj] * h0j;
            ah += wh1[jj] * h1j;
        }
        sp0[tid] = a0;
        sp1[tid] = aw + ah;
        __syncthreads();

        // phase 2: combine halves + activations (4 waves; gate type = tid>>6 wave-uniform)
        if (tid < G4) {
            const int xk = sx[k < Tlen ? k : (Tlen - 1)];
            float A0 = sp0[tid] + sp0[tid + 256] + sG0[xk * G4 + tid];
            float A1 = sp1[tid] + sp1[tid + 256] + b1;
            const bool isg = ((tid >> 6) == 2);
            sact0[tid] = isg ? tanh_(A0) : sigm(A0);
            sact1[tid] = isg ? tanh_(A1) : sigm(A1);
        }
        __syncthreads();

        // phase 3: state update
        if (tid < HDIM) {                     // wave 0: layer0 state
            if (k < Tlen) {
                float gi = sact0[tid], gf = sact0[HDIM + tid];
                float gg = sact0[2*HDIM + tid], go = sact0[3*HDIM + tid];
                c0 = gf * c0 + gi * gg;
                sh0[tid] = go * tanh_(c0);
            }
        } else if (tid < 2 * HDIM) {          // wave 1: layer1 state
            if (k >= 1) {
                int j = tid - HDIM;
                float gi = sact1[j], gf = sact1[HDIM + j];
                float gg = sact1[2*HDIM + j], go = sact1[3*HDIM + j];
                c1 = gf * c1 + gi * gg;
                sh1[j] = go * tanh_(c1);
            }
        }
        __syncthreads();
        vh0 = sh0[lane];
        vh1 = sh1[lane];
    }

    // logits = h1(T-1) @ Wfc^T + bfc
    if (tid < VOC) {
        float acc = bfc[tid];
        #pragma unroll
        for (int j = 0; j < HDIM; ++j)
            acc += Wfc[tid * HDIM + j] * sh1[j];
        out[b * VOC + tid] = acc;
    }
}

extern "C" void kernel_launch(void* const* d_in, const int* in_sizes, int n_in,
                              void* d_out, int out_size, void* d_ws, size_t ws_size,
                              hipStream_t stream) {
    const int*   x    = (const int*)  d_in[0];
    const float* emb  = (const float*)d_in[1];
    const float* Wih0 = (const float*)d_in[2];
    const float* Whh0 = (const float*)d_in[3];
    const float* bih0 = (const float*)d_in[4];
    const float* bhh0 = (const float*)d_in[5];
    const float* Wih1 = (const float*)d_in[6];
    const float* Whh1 = (const float*)d_in[7];
    const float* bih1 = (const float*)d_in[8];
    const float* bhh1 = (const float*)d_in[9];
    const float* Wfc  = (const float*)d_in[10];
    const float* bfc  = (const float*)d_in[11];
    float* out = (float*)d_out;
    float* ws  = (float*)d_ws;

    hipLaunchKernelGGL(precompute_kernel, dim3(VOC + 1), dim3(G4), 0, stream,
                       emb, Wih0, bih0, bhh0, bih1, bhh1, ws);
    hipLaunchKernelGGL(lstm_kernel, dim3(Bsz), dim3(NT), 0, stream,
                       x, Whh0, Wih1, Whh1, Wfc, bfc, ws, out);
}

// Round 3
// 921.726 us; speedup vs baseline: 2.4875x; 2.4875x over previous
//
#include <hip/hip_runtime.h>

#define Bsz   1024
#define Tlen  512
#define VOC   8
#define EDIM  32
#define HDIM  64
#define G4    256   // 4*H gate rows

typedef _Float16 half2_t __attribute__((ext_vector_type(2)));
typedef unsigned int u32x16 __attribute__((ext_vector_type(16)));

__device__ __forceinline__ unsigned rlu(unsigned v, int l) {
    return __builtin_amdgcn_readlane(v, l);   // l is compile-time-constant at every call site
}

// 2-way f16 dot with f32 accumulate (v_dot2_f32_f16)
__device__ __forceinline__ float dot2(unsigned wp, unsigned hp, float acc) {
#if __has_builtin(__builtin_amdgcn_fdot2)
    return __builtin_amdgcn_fdot2(__builtin_bit_cast(half2_t, wp),
                                  __builtin_bit_cast(half2_t, hp), acc, false);
#else
    half2_t w = __builtin_bit_cast(half2_t, wp);
    half2_t h = __builtin_bit_cast(half2_t, hp);
    return acc + (float)w[0] * (float)h[0] + (float)w[1] * (float)h[1];
#endif
}

__device__ __forceinline__ float sigm(float x) {
    return 1.0f / (1.0f + __expf(-x));
}
__device__ __forceinline__ float tanh_(float x) {
    float e2 = __expf(-2.0f * fabsf(x));
    float t  = (1.0f - e2) / (1.0f + e2);
    return copysignf(t, x);
}

// ws layout: [0 .. 8*256) = layer0 gate table from embedding (incl. both biases), fp32
//            [8*256 .. 8*256+256) = bih1+bhh1
__global__ void precompute_kernel(const float* __restrict__ emb,
                                  const float* __restrict__ Wih0,
                                  const float* __restrict__ bih0,
                                  const float* __restrict__ bhh0,
                                  const float* __restrict__ bih1,
                                  const float* __restrict__ bhh1,
                                  float* __restrict__ ws) {
    int g = threadIdx.x;
    int v = blockIdx.x;
    if (v < VOC) {
        float acc = bih0[g] + bhh0[g];
        #pragma unroll
        for (int e = 0; e < EDIM; ++e)
            acc += Wih0[g * EDIM + e] * emb[v * EDIM + e];
        ws[v * G4 + g] = acc;
    } else {
        ws[VOC * G4 + g] = bih1[g] + bhh1[g];
    }
}

__global__ __launch_bounds__(256, 2)
void lstm_kernel(const int*   __restrict__ x,
                 const float* __restrict__ Whh0,
                 const float* __restrict__ Wih1,
                 const float* __restrict__ Whh1,
                 const float* __restrict__ Wfc,
                 const float* __restrict__ bfc,
                 const float* __restrict__ ws,
                 float* __restrict__ out) {
    __shared__ float sG0[VOC * G4];             // 8 KB fp32 gate table
    __shared__ int   sx[Tlen];                  // 2 KB token stream
    __shared__ __align__(16) float sh0[HDIM];
    __shared__ __align__(16) float sh1[HDIM];
    __shared__ float sact0[G4], sact1[G4];

    const int tid  = threadIdx.x;
    const int b    = blockIdx.x;
    const int lane = tid & 63;
    const int g    = tid;                       // gate row 0..255

    // stage gate table + tokens
    #pragma unroll
    for (int i = 0; i < (VOC * G4) / 256; ++i)
        sG0[i * 256 + tid] = ws[i * 256 + tid];
    #pragma unroll
    for (int i = 0; i < Tlen / 256; ++i)
        sx[i * 256 + tid] = x[b * Tlen + i * 256 + tid];
    if (tid < HDIM) { sh0[tid] = 0.0f; sh1[tid] = 0.0f; }
    const float b1 = ws[VOC * G4 + g];

    // thread g owns gate-row g of all three matrices, f16-packed:
    // 32 pairs per matrix -> two u32x16 named vector values (no allocas).
    u32x16 w0a, w0b, wia, wib, wha, whb;
#define LOADROW(pa, pb, ptr) { const float4* pp_ = (const float4*)(ptr);          \
    _Pragma("unroll") for (int i_ = 0; i_ < 8; ++i_) { float4 t_ = pp_[i_];       \
        half2_t q0_, q1_;                                                          \
        q0_[0] = (_Float16)t_.x; q0_[1] = (_Float16)t_.y;                          \
        q1_[0] = (_Float16)t_.z; q1_[1] = (_Float16)t_.w;                          \
        pa[2*i_]   = __builtin_bit_cast(unsigned, q0_);                            \
        pa[2*i_+1] = __builtin_bit_cast(unsigned, q1_); }                          \
    _Pragma("unroll") for (int i_ = 0; i_ < 8; ++i_) { float4 t_ = pp_[8 + i_];   \
        half2_t q0_, q1_;                                                          \
        q0_[0] = (_Float16)t_.x; q0_[1] = (_Float16)t_.y;                          \
        q1_[0] = (_Float16)t_.z; q1_[1] = (_Float16)t_.w;                          \
        pb[2*i_]   = __builtin_bit_cast(unsigned, q0_);                            \
        pb[2*i_+1] = __builtin_bit_cast(unsigned, q1_); } }
    LOADROW(w0a, w0b, Whh0 + g * HDIM)
    LOADROW(wia, wib, Wih1 + g * HDIM)
    LOADROW(wha, whb, Whh1 + g * HDIM)
#undef LOADROW

    float c0 = 0.0f, c1 = 0.0f;        // lane j of wave0 holds c0[j]; wave1 holds c1[j]
    unsigned vh0p = 0u, vh1p = 0u;     // lane m: f16 pack of (h[2m], h[2m+1]); h=0 -> pack 0
    __syncthreads();

    // layer1 pipelined one step behind layer0: iter k does layer0@t=k and layer1@t=k-1
    #pragma unroll 1
    for (int k = 0; k <= Tlen; ++k) {
        const int xk = sx[k < Tlen ? k : (Tlen - 1)];
        float a0x = sG0[xk * G4 + g], a0y = 0.0f;
        float a1x = b1, a1y = 0.0f, a1z = 0.0f, a1w = 0.0f;
        #pragma unroll
        for (int m = 0; m < 16; ++m) {
            unsigned h0p = rlu(vh0p, m);
            unsigned h1p = rlu(vh1p, m);
            a0x = dot2(w0a[m], h0p, a0x);
            a1x = dot2(wia[m], h0p, a1x);
            a1z = dot2(wha[m], h1p, a1z);
        }
        #pragma unroll
        for (int m = 0; m < 16; ++m) {
            unsigned h0p = rlu(vh0p, 16 + m);
            unsigned h1p = rlu(vh1p, 16 + m);
            a0y = dot2(w0b[m], h0p, a0y);
            a1y = dot2(wib[m], h0p, a1y);
            a1w = dot2(whb[m], h1p, a1w);
        }
        float a0 = a0x + a0y;
        float a1 = (a1x + a1y) + (a1z + a1w);
        // wave-uniform activation select (wave id == gate type: 0=i 1=f 2=g 3=o)
        const bool isg = ((tid >> 6) == 2);
        sact0[tid] = isg ? tanh_(a0) : sigm(a0);
        sact1[tid] = isg ? tanh_(a1) : sigm(a1);
        __syncthreads();

        if (tid < HDIM) {                     // wave 0: layer0 state update
            if (k < Tlen) {
                float gi = sact0[tid], gf = sact0[HDIM + tid];
                float gg = sact0[2*HDIM + tid], go = sact0[3*HDIM + tid];
                c0 = gf * c0 + gi * gg;
                sh0[tid] = go * tanh_(c0);
            }
        } else if (tid < 2 * HDIM) {          // wave 1: layer1 state update
            if (k >= 1) {
                int j = tid - HDIM;
                float gi = sact1[j], gf = sact1[HDIM + j];
                float gg = sact1[2*HDIM + j], go = sact1[3*HDIM + j];
                c1 = gf * c1 + gi * gg;
                sh1[j] = go * tanh_(c1);
            }
        }
        __syncthreads();

        // repack updated h into per-lane f16 pairs for next step's readlane broadcast
        {
            const int lp = lane & 31;
            float2 h0 = *(const float2*)&sh0[2 * lp];
            float2 h1 = *(const float2*)&sh1[2 * lp];
            vh0p = __builtin_bit_cast(unsigned, __builtin_amdgcn_cvt_pkrtz(h0.x, h0.y));
            vh1p = __builtin_bit_cast(unsigned, __builtin_amdgcn_cvt_pkrtz(h1.x, h1.y));
        }
    }

    // logits = h1(T-1) @ Wfc^T + bfc   (exact fp32)
    if (tid < VOC) {
        float acc = bfc[tid];
        #pragma unroll
        for (int j = 0; j < HDIM; ++j)
            acc += Wfc[tid * HDIM + j] * sh1[j];
        out[b * VOC + tid] = acc;
    }
}

extern "C" void kernel_launch(void* const* d_in, const int* in_sizes, int n_in,
                              void* d_out, int out_size, void* d_ws, size_t ws_size,
                              hipStream_t stream) {
    const int*   x    = (const int*)  d_in[0];
    const float* emb  = (const float*)d_in[1];
    const float* Wih0 = (const float*)d_in[2];
    const float* Whh0 = (const float*)d_in[3];
    const float* bih0 = (const float*)d_in[4];
    const float* bhh0 = (const float*)d_in[5];
    const float* Wih1 = (const float*)d_in[6];
    const float* Whh1 = (const float*)d_in[7];
    const float* bih1 = (const float*)d_in[8];
    const float* bhh1 = (const float*)d_in[9];
    const float* Wfc  = (const float*)d_in[10];
    const float* bfc  = (const float*)d_in[11];
    float* out = (float*)d_out;
    float* ws  = (float*)d_ws;

    hipLaunchKernelGGL(precompute_kernel, dim3(VOC + 1), dim3(G4), 0, stream,
                       emb, Wih0, bih0, bhh0, bih1, bhh1, ws);
    hipLaunchKernelGGL(lstm_kernel, dim3(Bsz), dim3(G4), 0, stream,
                       x, Whh0, Wih1, Whh1, Wfc, bfc, ws, out);
}

// Round 4
// 453.833 us; speedup vs baseline: 5.0521x; 2.0310x over previous
//
#include <hip/hip_runtime.h>

#define Bsz   1024
#define Tlen  512
#define VOC   8
#define EDIM  32
#define HDIM  64
#define G4    256
#define SEQB  16                 // sequences per block
#define NT    512                // 8 waves
#define NBLK  (Bsz / SEQB)       // 64 blocks
#define TBLP  260                // padded table row stride (banks spread)

typedef _Float16 f16x8 __attribute__((ext_vector_type(8)));
typedef float    f32x4 __attribute__((ext_vector_type(4)));

__device__ __forceinline__ float ex2(float x) {
#if __has_builtin(__builtin_amdgcn_exp2f)
    return __builtin_amdgcn_exp2f(x);
#else
    return exp2f(x);
#endif
}
__device__ __forceinline__ float rcp_(float x) {
#if __has_builtin(__builtin_amdgcn_rcpf)
    return __builtin_amdgcn_rcpf(x);
#else
    return 1.0f / x;
#endif
}
__device__ __forceinline__ float sigm(float x) {
    return rcp_(1.0f + ex2(x * -1.4426950408889634f));
}
__device__ __forceinline__ float tanh_(float x) {
    // tanh(x) = 2/(1+e^{-2x}) - 1 ; saturates correctly at +/-inf
    return __builtin_fmaf(2.0f, rcp_(1.0f + ex2(x * -2.8853900817779268f)), -1.0f);
}

// ws: [0 .. 8*256) layer0 gate table (embedding @ Wih0^T + bih0 + bhh0), fp32
//     [8*256 .. 8*256+256) bih1+bhh1
__global__ void precompute_kernel(const float* __restrict__ emb,
                                  const float* __restrict__ Wih0,
                                  const float* __restrict__ bih0,
                                  const float* __restrict__ bhh0,
                                  const float* __restrict__ bih1,
                                  const float* __restrict__ bhh1,
                                  float* __restrict__ ws) {
    int g = threadIdx.x;
    int v = blockIdx.x;
    if (v < VOC) {
        float acc = bih0[g] + bhh0[g];
        #pragma unroll
        for (int e = 0; e < EDIM; ++e)
            acc += Wih0[g * EDIM + e] * emb[v * EDIM + e];
        ws[v * G4 + g] = acc;
    } else {
        ws[VOC * G4 + g] = bih1[g] + bhh1[g];
    }
}

// h LDS layout = A-fragment order for mfma_f32_16x16x32_f16:
//   chunk kc (k in [32kc,32kc+32)): lane lf reads 8 f16 = h[lf&15][kc*32+(lf>>4)*8 + 0..7]
//   stored at elem offset kc*512 + ((lf*8) ^ ((lf&3)<<7))   (XOR spreads row banks)
__device__ __forceinline__ f16x8 read_h_frag(const _Float16* hb, int kc, int l) {
    int off = kc * 512 + ((l * 8) ^ ((l & 3) << 7));
    return *(const f16x8*)(hb + off);
}
__device__ __forceinline__ void write_h(_Float16* hb, int r, int c, float v) {
    int off = (c >> 5) * 512 +
              (((((c & 31) >> 3) * 128) + r * 8 + (c & 7)) ^ ((r & 3) << 7));
    hb[off] = (_Float16)v;
}

__global__ __launch_bounds__(NT)
void lstm_kernel(const int*   __restrict__ x,
                 const float* __restrict__ Whh0,
                 const float* __restrict__ Wih1,
                 const float* __restrict__ Whh1,
                 const float* __restrict__ Wfc,
                 const float* __restrict__ bfc,
                 const float* __restrict__ ws,
                 float* __restrict__ out) {
    __shared__ float     stbl[VOC * TBLP];          // gate table, padded rows
    __shared__ int       sxl[SEQB * Tlen];          // tokens [r][t]
    __shared__ _Float16  hbuf[2][2][1024];          // [buf][layer][frag elems]
    __shared__ float     sh1f[SEQB][HDIM + 1];      // final h1, fp32, padded

    const int tid  = threadIdx.x;
    const int b0   = blockIdx.x * SEQB;
    const int l    = tid & 63;
    const int wid  = tid >> 6;
    const bool isL1 = (wid >= 4);
    const int w    = wid & 3;            // hidden-slice index: cols [16w,16w+16)
    const int l15  = l & 15;
    const int kb   = (l >> 4) * 8;       // K sub-offset within a 32-chunk

    for (int i = tid; i < VOC * G4; i += NT)
        stbl[(i >> 8) * TBLP + (i & 255)] = ws[i];
    for (int i = tid; i < SEQB * Tlen; i += NT)
        sxl[i] = x[b0 * Tlen + i];
    for (int i = tid; i < 2 * 2 * 1024; i += NT)
        ((_Float16*)hbuf)[i] = (_Float16)0.0f;

    // loop-invariant weight B-fragments: lane l holds W[col=16*(w+4q)+l15][kc*32+kb+i]
    f16x8 wA[4][2], wI[4][2], wH[4][2];
    float b1v[4];
    if (!isL1) {
        #pragma unroll
        for (int q = 0; q < 4; ++q) {
            const int cq = 64 * q + 16 * w + l15;
            #pragma unroll
            for (int kc = 0; kc < 2; ++kc) {
                const float* p = Whh0 + cq * HDIM + kc * 32 + kb;
                #pragma unroll
                for (int i = 0; i < 8; ++i) wA[q][kc][i] = (_Float16)p[i];
            }
        }
    } else {
        #pragma unroll
        for (int q = 0; q < 4; ++q) {
            const int cq = 64 * q + 16 * w + l15;
            b1v[q] = ws[VOC * G4 + cq];
            #pragma unroll
            for (int kc = 0; kc < 2; ++kc) {
                const float* p  = Wih1 + cq * HDIM + kc * 32 + kb;
                const float* p2 = Whh1 + cq * HDIM + kc * 32 + kb;
                #pragma unroll
                for (int i = 0; i < 8; ++i) {
                    wI[q][kc][i] = (_Float16)p[i];
                    wH[q][kc][i] = (_Float16)p2[i];
                }
            }
        }
    }

    float cst[4] = {0.0f, 0.0f, 0.0f, 0.0f};  // cell state: rows (l>>4)*4+i, col 16w+l15
    __syncthreads();

    // iter k: layer0 gates for t=k (h0 snap = h0(k-1)), layer1 gates for t=k-1
    // (h0 snap = h0(k-1) = layer1 input at t=k-1; h1 snap = h1(k-2)). One barrier/step.
    #pragma unroll 1
    for (int k = 0; k <= Tlen; ++k) {
        const int cur = k & 1, nxt = cur ^ 1;
        const _Float16* h0b = hbuf[cur][0];
        f16x8 a0 = read_h_frag(h0b, 0, l);
        f16x8 a1 = read_h_frag(h0b, 1, l);
        f32x4 acc[4];
        if (!isL1) {
            #pragma unroll
            for (int q = 0; q < 4; ++q) {
                acc[q] = (f32x4)(0.0f);
                acc[q] = __builtin_amdgcn_mfma_f32_16x16x32_f16(a0, wA[q][0], acc[q], 0, 0, 0);
                acc[q] = __builtin_amdgcn_mfma_f32_16x16x32_f16(a1, wA[q][1], acc[q], 0, 0, 0);
            }
            const int kk = (k < Tlen) ? k : (Tlen - 1);
            int tok[4];
            #pragma unroll
            for (int i = 0; i < 4; ++i)
                tok[i] = sxl[((l >> 4) * 4 + i) * Tlen + kk];
            #pragma unroll
            for (int q = 0; q < 4; ++q) {
                #pragma unroll
                for (int i = 0; i < 4; ++i)
                    acc[q][i] += stbl[tok[i] * TBLP + 64 * q + 16 * w + l15];
            }
        } else {
            const _Float16* h1b = hbuf[cur][1];
            f16x8 b0f = read_h_frag(h1b, 0, l);
            f16x8 b1f = read_h_frag(h1b, 1, l);
            #pragma unroll
            for (int q = 0; q < 4; ++q) {
                acc[q] = (f32x4)(b1v[q]);
                acc[q] = __builtin_amdgcn_mfma_f32_16x16x32_f16(a0,  wI[q][0], acc[q], 0, 0, 0);
                acc[q] = __builtin_amdgcn_mfma_f32_16x16x32_f16(a1,  wI[q][1], acc[q], 0, 0, 0);
                acc[q] = __builtin_amdgcn_mfma_f32_16x16x32_f16(b0f, wH[q][0], acc[q], 0, 0, 0);
                acc[q] = __builtin_amdgcn_mfma_f32_16x16x32_f16(b1f, wH[q][1], acc[q], 0, 0, 0);
            }
        }

        const bool doUpd = isL1 ? (k >= 1) : (k < Tlen);
        if (doUpd) {
            _Float16* hw = hbuf[nxt][isL1 ? 1 : 0];
            #pragma unroll
            for (int i = 0; i < 4; ++i) {
                float gi = sigm(acc[0][i]);
                float gf = sigm(acc[1][i]);
                float gg = tanh_(acc[2][i]);
                float go = sigm(acc[3][i]);
                cst[i] = gf * cst[i] + gi * gg;
                float hv = go * tanh_(cst[i]);
                const int r  = (l >> 4) * 4 + i;
                const int cc = 16 * w + l15;
                if (isL1 && k == Tlen) sh1f[r][cc] = hv;   // final h1 in fp32
                else                   write_h(hw, r, cc, hv);
            }
        }
        __syncthreads();
    }

    // logits = h1(T-1) @ Wfc^T + bfc  (fp32)
    if (tid < SEQB * VOC) {
        const int seq = tid >> 3, v = tid & 7;
        float acc2 = bfc[v];
        #pragma unroll
        for (int j = 0; j < HDIM; ++j)
            acc2 += Wfc[v * HDIM + j] * sh1f[seq][j];
        out[(b0 + seq) * VOC + v] = acc2;
    }
}

extern "C" void kernel_launch(void* const* d_in, const int* in_sizes, int n_in,
                              void* d_out, int out_size, void* d_ws, size_t ws_size,
                              hipStream_t stream) {
    const int*   x    = (const int*)  d_in[0];
    const float* emb  = (const float*)d_in[1];
    const float* Wih0 = (const float*)d_in[2];
    const float* Whh0 = (const float*)d_in[3];
    const float* bih0 = (const float*)d_in[4];
    const float* bhh0 = (const float*)d_in[5];
    const float* Wih1 = (const float*)d_in[6];
    const float* Whh1 = (const float*)d_in[7];
    const float* bih1 = (const float*)d_in[8];
    const float* bhh1 = (const float*)d_in[9];
    const float* Wfc  = (const float*)d_in[10];
    const float* bfc  = (const float*)d_in[11];
    float* out = (float*)d_out;
    float* ws  = (float*)d_ws;

    hipLaunchKernelGGL(precompute_kernel, dim3(VOC + 1), dim3(G4), 0, stream,
                       emb, Wih0, bih0, bhh0, bih1, bhh1, ws);
    hipLaunchKernelGGL(lstm_kernel, dim3(NBLK), dim3(NT), 0, stream,
                       x, Whh0, Wih1, Whh1, Wfc, bfc, ws, out);
}